// Round 14
// baseline (383.008 us; speedup 1.0000x reference)
//
#include <hip/hip_runtime.h>
#include <math.h>

typedef __attribute__((ext_vector_type(8))) short short8v;  // 8 bf16 (4 VGPRs)
typedef __attribute__((ext_vector_type(4))) float f32x4;    // 4 fp32 acc

static __device__ __forceinline__ ushort f2bf(float f) {
  union { float f; unsigned u; } v; v.f = f;
  unsigned r = v.u + 0x7FFF + ((v.u >> 16) & 1);  // RNE
  return (ushort)(r >> 16);
}
static __device__ __forceinline__ float bflo(unsigned p) {  // low bf16 of packed pair
  union { unsigned u; float f; } v; v.u = p << 16; return v.f;
}
static __device__ __forceinline__ float bfhi(unsigned p) {  // high bf16
  union { unsigned u; float f; } v; v.u = p & 0xFFFF0000u; return v.f;
}

// ---------------- CSR build ----------------

__global__ void zero_ints(int* __restrict__ a, int n) {
  int i = blockIdx.x * blockDim.x + threadIdx.x;
  if (i < n) a[i] = 0;
}

__global__ void count_dst(const int* __restrict__ dst, int* __restrict__ cnt, int E) {
  int e = blockIdx.x * blockDim.x + threadIdx.x;
  if (e < E) atomicAdd(&cnt[dst[e]], 1);
}

// ---- 3-phase multi-block scan; requires ceil(N/256) <= 256 (N <= 65536) ----

__global__ __launch_bounds__(256) void scan_blocksums(const int* __restrict__ cnt,
                                                      int* __restrict__ bsum,
                                                      int N, int chunk) {
  __shared__ int red[256];
  int t = threadIdx.x, b = blockIdx.x;
  int i = b * chunk + t;
  red[t] = (t < chunk && i < N) ? cnt[i] : 0;
  __syncthreads();
#pragma unroll
  for (int off = 128; off > 0; off >>= 1) {
    if (t < off) red[t] += red[t + off];
    __syncthreads();
  }
  if (t == 0) bsum[b] = red[0];
}

__global__ __launch_bounds__(256) void scan_offsets(const int* __restrict__ bsum,
                                                    int* __restrict__ boff,
                                                    int* __restrict__ rowptr, int N) {
  __shared__ int s[256];
  int t = threadIdx.x;
  int v = bsum[t];
  s[t] = v;
  __syncthreads();
#pragma unroll
  for (int off = 1; off < 256; off <<= 1) {
    int u = (t >= off) ? s[t - off] : 0;
    __syncthreads();
    s[t] += u;
    __syncthreads();
  }
  boff[t] = s[t] - v;
  if (t == 255) rowptr[N] = s[255];
}

// writes rowptr, dinv, and cursor (= rowptr copy, so fill_csr needs no rowptr read)
__global__ __launch_bounds__(256) void scan_write(const int* __restrict__ cnt,
                                                  const int* __restrict__ boff,
                                                  int* __restrict__ rowptr,
                                                  int* __restrict__ cursor,
                                                  float* __restrict__ dinv,
                                                  int N, int chunk) {
  __shared__ int s[256];
  int t = threadIdx.x, b = blockIdx.x;
  int i = b * chunk + t;
  int c = (t < chunk && i < N) ? cnt[i] : 0;
  s[t] = c;
  __syncthreads();
#pragma unroll
  for (int off = 1; off < 256; off <<= 1) {
    int u = (t >= off) ? s[t - off] : 0;
    __syncthreads();
    s[t] += u;
    __syncthreads();
  }
  if (t < chunk && i < N) {
    int rp = boff[b] + s[t] - c;
    rowptr[i] = rp;
    cursor[i] = rp;
    dinv[i] = rsqrtf((float)c + 1.0f);  // +1 self-loop
  }
}

// packed CSR entry: low 32b = src node, high 32b = f32 bits of norm weight.
// Non-temporal 8B store: csr is write-once (read only by later dispatches),
// so bypass L2 to avoid fetch-merge-writeback on random lines.
__global__ void fill_csr(const int* __restrict__ src, const int* __restrict__ dst,
                         const float* __restrict__ dinv, int* __restrict__ cursor,
                         long long* __restrict__ csr, int E) {
  int e = blockIdx.x * blockDim.x + threadIdx.x;
  if (e >= E) return;
  int d = dst[e], s = src[e];
  int idx = atomicAdd(&cursor[d], 1);  // cursor pre-seeded with rowptr
  float w = dinv[s] * dinv[d];
  long long v = ((long long)(unsigned)__float_as_int(w) << 32) | (unsigned)s;
  __builtin_nontemporal_store(v, &csr[idx]);
}

// ---------------- W -> bf16 B-fragment layout: Wb[kb*1024 + n*8 + j] = W[kb*8+j][n] ----------------

__global__ __launch_bounds__(256) void transform_w(const float* __restrict__ W1,
                                                   const float* __restrict__ W2,
                                                   const float* __restrict__ W3,
                                                   ushort* __restrict__ Wb1,
                                                   ushort* __restrict__ Wb2,
                                                   ushort* __restrict__ Wb3) {
  const float* W = (blockIdx.x == 0) ? W1 : (blockIdx.x == 1) ? W2 : W3;
  ushort* Wb = (blockIdx.x == 0) ? Wb1 : (blockIdx.x == 1) ? Wb2 : Wb3;
  for (int i = threadIdx.x; i < 16384; i += 256) {
    int kb = i >> 10, rem = i & 1023, n = rem >> 3, j = rem & 7;
    Wb[i] = f2bf(W[(kb * 8 + j) * 128 + n]);
  }
}

// ---------------- MFMA GEMM: Hb[N,128](bf16) = A[N,128] @ W[128,128] ----------------
// 256 thr = 4 waves, 64 rows/block. A staged to LDS bf16 [64][136] (pad kills bank conflicts).
// Wb (B-frag layout) staged 32KB to LDS. Per wave: 16 rows, 8 col-tiles, 4 K-steps of
// mfma_f32_16x16x32_bf16. Layouts: A/B lane l -> row/col l&15, k=(l>>4)*8+j;
// C/D col=lane&15, row=(lane>>4)*4+reg (m89-verified).

template<bool AF32>
__global__ __launch_bounds__(256) void gemm_mfma(const void* __restrict__ Av,
                                                 const ushort* __restrict__ Wb,
                                                 ushort* __restrict__ Hb, int N) {
  __shared__ __align__(16) ushort As[64 * 136];
  __shared__ __align__(16) ushort Ws[16384];
  int tid = threadIdx.x;
  int row0 = blockIdx.x * 64;
  {  // stage W: 32KB = 2048 int4
    const int4* s = (const int4*)Wb;
    int4* d = (int4*)Ws;
#pragma unroll
    for (int i = 0; i < 8; ++i) d[tid + 256 * i] = s[tid + 256 * i];
  }
  if (AF32) {  // stage A from f32, convert
    const float4* A4 = (const float4*)Av;
#pragma unroll
    for (int i = 0; i < 8; ++i) {
      int idx = tid + 256 * i;          // 2048 float4
      int r = idx >> 5, k4 = idx & 31;
      int grow = row0 + r;
      float4 v = make_float4(0.f, 0.f, 0.f, 0.f);
      if (grow < N) v = A4[(size_t)grow * 32 + k4];
      ushort4 u;
      u.x = f2bf(v.x); u.y = f2bf(v.y); u.z = f2bf(v.z); u.w = f2bf(v.w);
      *(ushort4*)&As[r * 136 + k4 * 4] = u;
    }
  } else {  // stage A from bf16
    const int4* A8 = (const int4*)Av;
#pragma unroll
    for (int i = 0; i < 4; ++i) {
      int idx = tid + 256 * i;          // 1024 chunks of 8 bf16
      int r = idx >> 4, k8 = idx & 15;
      int grow = row0 + r;
      int4 v = make_int4(0, 0, 0, 0);
      if (grow < N) v = A8[(size_t)grow * 16 + k8];
      *(int4*)&As[r * 136 + k8 * 8] = v;
    }
  }
  __syncthreads();
  int wave = tid >> 6, lane = tid & 63;
  int lrow = lane & 15, kb = lane >> 4;  // kb in 0..3
  short8v a[4];
#pragma unroll
  for (int s = 0; s < 4; ++s)
    a[s] = *(const short8v*)&As[(wave * 16 + lrow) * 136 + s * 32 + kb * 8];
#pragma unroll
  for (int c = 0; c < 8; ++c) {
    f32x4 acc = {0.f, 0.f, 0.f, 0.f};
#pragma unroll
    for (int s = 0; s < 4; ++s) {
      short8v b = *(const short8v*)&Ws[(4 * s + kb) * 1024 + (c * 16 + lrow) * 8];
      acc = __builtin_amdgcn_mfma_f32_16x16x32_bf16(a[s], b, acc, 0, 0, 0);
    }
    int col = c * 16 + lrow;
    int r = row0 + wave * 16 + kb * 4;
#pragma unroll
    for (int j = 0; j < 4; ++j)
      if (r + j < N) Hb[(size_t)(r + j) * 128 + col] = f2bf(acc[j]);
  }
}

// ---------------- aggregation: out = S*H + b (gather bf16 H, f32 accumulate) ----------------
// Wave per dst node; packed (src,w) one-per-lane per 64-edge chunk, __shfl broadcast;
// 8 independent gathers in flight (latency-bound on L2/L3 random row reads).
// Accumulation order identical to sequential CSR order.

__global__ __launch_bounds__(256) void agg_csr(const ushort* __restrict__ Hb,
                                               const long long* __restrict__ csr,
                                               const int* __restrict__ rowptr,
                                               const float* __restrict__ dinv,
                                               const float* __restrict__ b,
                                               float* __restrict__ outf,
                                               ushort* __restrict__ outb, int N) {
  int node = blockIdx.x * 4 + (threadIdx.x >> 6);
  if (node >= N) return;
  int lane = threadIdx.x & 63;
  int beg = rowptr[node];
  int deg = rowptr[node + 1] - beg;
  float di = dinv[node];
  float sw = di * di;  // self-loop norm
  const unsigned* H2 = (const unsigned*)Hb;  // 2 bf16 per u32
  unsigned hp = H2[(size_t)node * 64 + lane];
  float ax = bflo(hp) * sw, ay = bfhi(hp) * sw;
  for (int base = 0; base < deg; base += 64) {
    int m = deg - base; if (m > 64) m = 64;
    int smy = 0; float wmy = 0.f;
    if (lane < m) {
      long long c = csr[beg + base + lane];
      smy = (int)(unsigned)(c & 0xFFFFFFFFll);
      wmy = __int_as_float((int)(c >> 32));
    }
    int j = 0;
    for (; j + 8 <= m; j += 8) {
      int s0 = __shfl(smy, j),     s1 = __shfl(smy, j + 1);
      int s2 = __shfl(smy, j + 2), s3 = __shfl(smy, j + 3);
      int s4 = __shfl(smy, j + 4), s5 = __shfl(smy, j + 5);
      int s6 = __shfl(smy, j + 6), s7 = __shfl(smy, j + 7);
      float w0 = __shfl(wmy, j),     w1 = __shfl(wmy, j + 1);
      float w2 = __shfl(wmy, j + 2), w3 = __shfl(wmy, j + 3);
      float w4 = __shfl(wmy, j + 4), w5 = __shfl(wmy, j + 5);
      float w6 = __shfl(wmy, j + 6), w7 = __shfl(wmy, j + 7);
      unsigned p0 = H2[(size_t)s0 * 64 + lane];
      unsigned p1 = H2[(size_t)s1 * 64 + lane];
      unsigned p2 = H2[(size_t)s2 * 64 + lane];
      unsigned p3 = H2[(size_t)s3 * 64 + lane];
      unsigned p4 = H2[(size_t)s4 * 64 + lane];
      unsigned p5 = H2[(size_t)s5 * 64 + lane];
      unsigned p6 = H2[(size_t)s6 * 64 + lane];
      unsigned p7 = H2[(size_t)s7 * 64 + lane];
      ax += bflo(p0) * w0; ay += bfhi(p0) * w0;
      ax += bflo(p1) * w1; ay += bfhi(p1) * w1;
      ax += bflo(p2) * w2; ay += bfhi(p2) * w2;
      ax += bflo(p3) * w3; ay += bfhi(p3) * w3;
      ax += bflo(p4) * w4; ay += bfhi(p4) * w4;
      ax += bflo(p5) * w5; ay += bfhi(p5) * w5;
      ax += bflo(p6) * w6; ay += bfhi(p6) * w6;
      ax += bflo(p7) * w7; ay += bfhi(p7) * w7;
    }
    for (; j + 4 <= m; j += 4) {
      int s0 = __shfl(smy, j),     s1 = __shfl(smy, j + 1);
      int s2 = __shfl(smy, j + 2), s3 = __shfl(smy, j + 3);
      float w0 = __shfl(wmy, j),     w1 = __shfl(wmy, j + 1);
      float w2 = __shfl(wmy, j + 2), w3 = __shfl(wmy, j + 3);
      unsigned p0 = H2[(size_t)s0 * 64 + lane];
      unsigned p1 = H2[(size_t)s1 * 64 + lane];
      unsigned p2 = H2[(size_t)s2 * 64 + lane];
      unsigned p3 = H2[(size_t)s3 * 64 + lane];
      ax += bflo(p0) * w0; ay += bfhi(p0) * w0;
      ax += bflo(p1) * w1; ay += bfhi(p1) * w1;
      ax += bflo(p2) * w2; ay += bfhi(p2) * w2;
      ax += bflo(p3) * w3; ay += bfhi(p3) * w3;
    }
    for (; j < m; ++j) {
      int s0 = __shfl(smy, j);
      float w0 = __shfl(wmy, j);
      unsigned p0 = H2[(size_t)s0 * 64 + lane];
      ax += bflo(p0) * w0; ay += bfhi(p0) * w0;
    }
  }
  float2 bb = ((const float2*)b)[lane];
  float rx = ax + bb.x, ry = ay + bb.y;
  if (outf) ((float2*)outf)[(size_t)node * 64 + lane] = make_float2(rx, ry);
  if (outb) {
    ushort2 u; u.x = f2bf(rx); u.y = f2bf(ry);
    *(ushort2*)&outb[(size_t)node * 128 + 2 * lane] = u;
  }
}

// ---------------- head: fold Wp1@Wp2, then per-node 128->16 + log_softmax ----------------

__global__ __launch_bounds__(256) void fuse_w(const float* __restrict__ Wp1,
                                              const float* __restrict__ bp1,
                                              const float* __restrict__ Wp2,
                                              const float* __restrict__ bp2,
                                              float* __restrict__ Wf, float* __restrict__ bf) {
  int tid = threadIdx.x;
  for (int o = tid; o < 2048; o += 256) {
    int r = o >> 4, j = o & 15;
    float s = 0.f;
    for (int k = 0; k < 128; ++k) s += Wp1[r * 128 + k] * Wp2[k * 16 + j];
    Wf[o] = s;
  }
  if (tid < 16) {
    float s = bp2[tid];
    for (int k = 0; k < 128; ++k) s += bp1[k] * Wp2[k * 16 + tid];
    bf[tid] = s;
  }
}

__global__ __launch_bounds__(256) void proj_kernel(const float* __restrict__ emb,
                                                   const float* __restrict__ Wf,
                                                   const float* __restrict__ bf,
                                                   float* __restrict__ out, int N) {
  __shared__ float Ws[2048];
  __shared__ float bfs[16];
  for (int i = threadIdx.x; i < 2048; i += 256) Ws[i] = Wf[i];
  if (threadIdx.x < 16) bfs[threadIdx.x] = bf[threadIdx.x];
  __syncthreads();
  int node = blockIdx.x * 4 + (threadIdx.x >> 6);
  if (node >= N) return;
  int lane = threadIdx.x & 63;
  int j = lane & 15, g = lane >> 4;
  const float* er = emb + (size_t)node * 128 + g * 32;
  float p = 0.f;
#pragma unroll
  for (int k = 0; k < 32; ++k) p += er[k] * Ws[(g * 32 + k) * 16 + j];
  p += __shfl_xor(p, 16);
  p += __shfl_xor(p, 32);
  p += bfs[j];
  float mx = p;
#pragma unroll
  for (int o = 1; o < 16; o <<= 1) mx = fmaxf(mx, __shfl_xor(mx, o));
  float ex = expf(p - mx);
  float sm = ex;
#pragma unroll
  for (int o = 1; o < 16; o <<= 1) sm += __shfl_xor(sm, o);
  float res = p - mx - logf(sm);
  if (lane < 16) out[(size_t)node * 16 + j] = res;
}

// ---------------- launch ----------------

extern "C" void kernel_launch(void* const* d_in, const int* in_sizes, int n_in,
                              void* d_out, int out_size, void* d_ws, size_t ws_size,
                              hipStream_t stream) {
  const float* x   = (const float*)d_in[0];
  const int*   ei  = (const int*)d_in[1];
  const float* W1  = (const float*)d_in[2];
  const float* b1  = (const float*)d_in[3];
  const float* W2  = (const float*)d_in[4];
  const float* b2  = (const float*)d_in[5];
  const float* W3  = (const float*)d_in[6];
  const float* b3  = (const float*)d_in[7];
  const float* Wp1 = (const float*)d_in[8];
  const float* bp1 = (const float*)d_in[9];
  const float* Wp2 = (const float*)d_in[10];
  const float* bp2 = (const float*)d_in[11];

  const int N = in_sizes[0] / 128;
  const int E = in_sizes[1] / 2;
  const int* src = ei;       // edge_index[0]
  const int* dst = ei + E;   // edge_index[1]

  float* out    = (float*)d_out;
  float* emb    = out;                    // [N,128] final embedding
  float* scores = out + (size_t)N * 128;  // [N,16]

  char* w = (char*)d_ws;
  auto alloc = [&](size_t bytes) {
    char* p = w;
    w += (bytes + 255) & ~(size_t)255;
    return p;
  };
  int*       cnt     = (int*)alloc((size_t)N * 4);
  int*       cursor  = (int*)alloc((size_t)N * 4);
  int*       rowptr  = (int*)alloc(((size_t)N + 1) * 4);
  float*     dinv    = (float*)alloc((size_t)N * 4);
  long long* csr     = (long long*)alloc((size_t)E * 8);     // packed (src, w)
  ushort*    Hb      = (ushort*)alloc((size_t)N * 128 * 2);  // gemm out (bf16)
  ushort*    Ab      = (ushort*)alloc((size_t)N * 128 * 2);  // agg out (bf16)
  ushort*    Wb1     = (ushort*)alloc(16384 * 2);
  ushort*    Wb2     = (ushort*)alloc(16384 * 2);
  ushort*    Wb3     = (ushort*)alloc(16384 * 2);
  float*     Wf      = (float*)alloc(2048 * 4);
  float*     bf      = (float*)alloc(16 * 4);
  int*       bsum    = (int*)alloc(256 * 4);
  int*       boff    = (int*)alloc(256 * 4);

  int gE = (E + 255) / 256;
  int chunk = (N + 255) / 256;  // <= 256 required (N <= 65536)

  zero_ints<<<(N + 255) / 256, 256, 0, stream>>>(cnt, N);
  count_dst<<<gE, 256, 0, stream>>>(dst, cnt, E);
  scan_blocksums<<<256, 256, 0, stream>>>(cnt, bsum, N, chunk);
  scan_offsets<<<1, 256, 0, stream>>>(bsum, boff, rowptr, N);
  scan_write<<<256, 256, 0, stream>>>(cnt, boff, rowptr, cursor, dinv, N, chunk);
  fill_csr<<<gE, 256, 0, stream>>>(src, dst, dinv, cursor, csr, E);
  transform_w<<<3, 256, 0, stream>>>(W1, W2, W3, Wb1, Wb2, Wb3);
  fuse_w<<<1, 256, 0, stream>>>(Wp1, bp1, Wp2, bp2, Wf, bf);

  int gemm_grid = (N + 63) / 64;
  int node_grid = (N + 3) / 4;
  gemm_mfma<true><<<gemm_grid, 256, 0, stream>>>(x, Wb1, Hb, N);
  agg_csr<<<node_grid, 256, 0, stream>>>(Hb, csr, rowptr, dinv, b1, nullptr, Ab, N);
  gemm_mfma<false><<<gemm_grid, 256, 0, stream>>>(Ab, Wb2, Hb, N);
  agg_csr<<<node_grid, 256, 0, stream>>>(Hb, csr, rowptr, dinv, b2, nullptr, Ab, N);
  gemm_mfma<false><<<gemm_grid, 256, 0, stream>>>(Ab, Wb3, Hb, N);
  agg_csr<<<node_grid, 256, 0, stream>>>(Hb, csr, rowptr, dinv, b3, emb, nullptr, N);
  proj_kernel<<<node_grid, 256, 0, stream>>>(emb, Wf, bf, scores, N);
}